// Round 1
// baseline (653.646 us; speedup 1.0000x reference)
//
#include <hip/hip_runtime.h>
#include <hip/hip_bf16.h>

#define NB 4
#define NT 2048
#define ND 1024
#define NH 16
#define NDH 64
#define NM (NB*NT)   // 8192 rows

typedef __bf16 bf16_t;
typedef bf16_t bf16x4 __attribute__((ext_vector_type(4)));
typedef bf16_t bf16x8 __attribute__((ext_vector_type(8)));
typedef float f32x4 __attribute__((ext_vector_type(4)));

__device__ __forceinline__ void gload_lds16(const bf16_t* g, bf16_t* l) {
  __builtin_amdgcn_global_load_lds(
      (const __attribute__((address_space(1))) unsigned int*)g,
      (__attribute__((address_space(3))) unsigned int*)l, 16, 0, 0);
}

// ---------------- fp32 -> bf16 convert (vectorized) ----------------
__global__ void cvt_f32_to_bf16(const float* __restrict__ in, bf16_t* __restrict__ out, int n4) {
  int i = blockIdx.x * blockDim.x + threadIdx.x;
  if (i >= n4) return;
  float4 v = ((const float4*)in)[i];
  bf16x4 o;
  o[0] = (bf16_t)v.x; o[1] = (bf16_t)v.y; o[2] = (bf16_t)v.z; o[3] = (bf16_t)v.w;
  ((bf16x4*)out)[i] = o;
}

// ---------------- W (K x N fp32) -> W^T (N x K bf16) ----------------
__global__ void transpose_cvt_kernel(const float* __restrict__ in, bf16_t* __restrict__ out) {
  __shared__ float tile[32][33];
  int n0 = blockIdx.x * 32, k0 = blockIdx.y * 32;
  int tx = threadIdx.x & 31, ty = threadIdx.x >> 5;
  #pragma unroll
  for (int r = ty; r < 32; r += 8)
    tile[r][tx] = in[(size_t)(k0 + r) * ND + n0 + tx];
  __syncthreads();
  #pragma unroll
  for (int r = ty; r < 32; r += 8)
    out[(size_t)(n0 + r) * ND + k0 + tx] = (bf16_t)tile[tx][r];
}

// ---------------- GEMM: C = A(MxK bf16) * B^T(NxK bf16) + bias ----------------
// OUT_MODE 0: bf16 out, head layout (B,H,T,DH)   [Q,K projections]
// OUT_MODE 1: bf16 out, V^T layout (B,H,DH,T)    [V projection]
// OUT_MODE 2: fp32 out, row-major (M,N)          [output projection]
template<int OUT_MODE>
__global__ void gemm_bt(const bf16_t* __restrict__ A, const bf16_t* __restrict__ Bt,
                        const float* __restrict__ bias, void* __restrict__ outp,
                        int M, int N, int K) {
  __shared__ bf16_t As[128 * 32];
  __shared__ bf16_t Bs[128 * 32];
  const int tid  = threadIdx.x;
  const int lane = tid & 63;
  const int wid  = tid >> 6;
  const int tm = blockIdx.x * 128;
  const int tn = blockIdx.y * 128;
  const int wr = wid >> 1, wc = wid & 1;
  const int lrow = lane & 15;
  const int lko  = (lane >> 4) << 3;

  // staging: 16B chunk c covers LDS row c>>2, k-offset (c&3)*8
  const int cA  = wid * 64 + lane;
  const int rA0 = cA >> 2;
  const int kA0 = (cA & 3) << 3;

  f32x4 acc[4][4];
  #pragma unroll
  for (int i = 0; i < 4; ++i)
    #pragma unroll
    for (int j = 0; j < 4; ++j) {
      f32x4 z = {0.f, 0.f, 0.f, 0.f};
      acc[i][j] = z;
    }

  for (int k0 = 0; k0 < K; k0 += 32) {
    gload_lds16(A  + (size_t)(tm + rA0)      * K + k0 + kA0, As + wid * 512);
    gload_lds16(A  + (size_t)(tm + rA0 + 64) * K + k0 + kA0, As + 2048 + wid * 512);
    gload_lds16(Bt + (size_t)(tn + rA0)      * K + k0 + kA0, Bs + wid * 512);
    gload_lds16(Bt + (size_t)(tn + rA0 + 64) * K + k0 + kA0, Bs + 2048 + wid * 512);
    __syncthreads();
    bf16x8 af[4], bfr[4];
    #pragma unroll
    for (int i = 0; i < 4; ++i)
      af[i] = *(const bf16x8*)&As[(wr * 64 + i * 16 + lrow) * 32 + lko];
    #pragma unroll
    for (int j = 0; j < 4; ++j)
      bfr[j] = *(const bf16x8*)&Bs[(wc * 64 + j * 16 + lrow) * 32 + lko];
    #pragma unroll
    for (int i = 0; i < 4; ++i)
      #pragma unroll
      for (int j = 0; j < 4; ++j)
        acc[i][j] = __builtin_amdgcn_mfma_f32_16x16x32_bf16(af[i], bfr[j], acc[i][j], 0, 0, 0);
    __syncthreads();
  }

  // epilogue: D layout col = lane&15, row = (lane>>4)*4 + reg
  const int rb = (lane >> 4) << 2;
  #pragma unroll
  for (int j = 0; j < 4; ++j) {
    int n = tn + wc * 64 + j * 16 + lrow;
    float bv = bias[n];
    #pragma unroll
    for (int i = 0; i < 4; ++i) {
      #pragma unroll
      for (int r = 0; r < 4; ++r) {
        int m = tm + wr * 64 + i * 16 + rb + r;
        float val = acc[i][j][r] + bv;
        if constexpr (OUT_MODE == 2) {
          ((float*)outp)[(size_t)m * ND + n] = val;
        } else {
          int b = m >> 11, t = m & (NT - 1);
          int h = n >> 6, dh = n & (NDH - 1);
          size_t idx;
          if constexpr (OUT_MODE == 0)
            idx = ((size_t)(b * NH + h) * NT + t) * NDH + dh;
          else
            idx = ((size_t)(b * NH + h) * NDH + dh) * NT + t;
          ((bf16_t*)outp)[idx] = (bf16_t)val;
        }
      }
    }
  }
}

// ---------------- causal flash attention ----------------
// Qh,Kh: (B,H,T,DH) bf16; Vt: (B,H,DH,T) bf16; ctx out: (B,T,D) bf16 row-major
__global__ void attn_kernel(const bf16_t* __restrict__ Qh, const bf16_t* __restrict__ Kh,
                            const bf16_t* __restrict__ Vt, bf16_t* __restrict__ ctx) {
  __shared__ bf16_t P_lds[4][16 * 32];
  const int tid  = threadIdx.x;
  const int lane = tid & 63;
  const int wid  = tid >> 6;
  const int bh   = blockIdx.x >> 5;       // (b*H + h), 32 q-blocks per head
  const int qblk = blockIdx.x & 31;
  const int r0   = qblk * 64 + wid * 16;  // this wave's first query row
  const int b = bh >> 4, h = bh & 15;

  const bf16_t* Qbh = Qh + (size_t)bh * NT * NDH;
  const bf16_t* Kbh = Kh + (size_t)bh * NT * NDH;
  const bf16_t* Vbh = Vt + (size_t)bh * NDH * NT;

  const int lrow = lane & 15;
  const int lko  = (lane >> 4) << 3;
  const int rb   = (lane >> 4) << 2;

  // Q fragments (rows r0+lrow, d-chunks 0..31 / 32..63)
  bf16x8 qf0 = *(const bf16x8*)&Qbh[(size_t)(r0 + lrow) * NDH + lko];
  bf16x8 qf1 = *(const bf16x8*)&Qbh[(size_t)(r0 + lrow) * NDH + 32 + lko];

  float mrow[4], lsum[4];
  f32x4 acc[4];
  #pragma unroll
  for (int r = 0; r < 4; ++r) { mrow[r] = -1e30f; lsum[r] = 0.f; }
  #pragma unroll
  for (int d = 0; d < 4; ++d) { f32x4 z = {0.f,0.f,0.f,0.f}; acc[d] = z; }

  bf16_t* pw = &P_lds[wid][0];

  for (int j0 = 0; j0 <= r0 + 15; j0 += 32) {
    f32x4 s0 = {0.f,0.f,0.f,0.f};
    f32x4 s1 = {0.f,0.f,0.f,0.f};
    {
      bf16x8 kf;
      kf = *(const bf16x8*)&Kbh[(size_t)(j0 + lrow) * NDH + lko];
      s0 = __builtin_amdgcn_mfma_f32_16x16x32_bf16(qf0, kf, s0, 0, 0, 0);
      kf = *(const bf16x8*)&Kbh[(size_t)(j0 + lrow) * NDH + 32 + lko];
      s0 = __builtin_amdgcn_mfma_f32_16x16x32_bf16(qf1, kf, s0, 0, 0, 0);
      kf = *(const bf16x8*)&Kbh[(size_t)(j0 + 16 + lrow) * NDH + lko];
      s1 = __builtin_amdgcn_mfma_f32_16x16x32_bf16(qf0, kf, s1, 0, 0, 0);
      kf = *(const bf16x8*)&Kbh[(size_t)(j0 + 16 + lrow) * NDH + 32 + lko];
      s1 = __builtin_amdgcn_mfma_f32_16x16x32_bf16(qf1, kf, s1, 0, 0, 0);
    }
    // scale + causal mask (rows rb+r at cols j0+{0,16}+lrow)
    const bool edge = (j0 + 31 > r0);
    #pragma unroll
    for (int r = 0; r < 4; ++r) {
      float a0 = s0[r] * 0.125f;
      float a1 = s1[r] * 0.125f;
      if (edge) {
        int gi = r0 + rb + r;
        if (j0 + lrow > gi)      a0 = -1e30f;
        if (j0 + 16 + lrow > gi) a1 = -1e30f;
      }
      s0[r] = a0; s1[r] = a1;
    }
    // online softmax: row stats across the 16 j-lanes of each group
    float tmax[4], psum[4];
    #pragma unroll
    for (int r = 0; r < 4; ++r) tmax[r] = fmaxf(s0[r], s1[r]);
    #pragma unroll
    for (int off = 1; off < 16; off <<= 1) {
      #pragma unroll
      for (int r = 0; r < 4; ++r) tmax[r] = fmaxf(tmax[r], __shfl_xor(tmax[r], off));
    }
    #pragma unroll
    for (int r = 0; r < 4; ++r) {
      float mn = fmaxf(mrow[r], tmax[r]);
      float alpha = __expf(mrow[r] - mn);
      mrow[r] = mn;
      lsum[r] *= alpha;
      acc[0][r] *= alpha; acc[1][r] *= alpha; acc[2][r] *= alpha; acc[3][r] *= alpha;
      float p0 = __expf(s0[r] - mn);
      float p1 = __expf(s1[r] - mn);
      s0[r] = p0; s1[r] = p1;
      psum[r] = p0 + p1;
    }
    #pragma unroll
    for (int off = 1; off < 16; off <<= 1) {
      #pragma unroll
      for (int r = 0; r < 4; ++r) psum[r] += __shfl_xor(psum[r], off);
    }
    #pragma unroll
    for (int r = 0; r < 4; ++r) lsum[r] += psum[r];

    // P (D-layout) -> LDS -> A-layout fragment (per-wave private, no barrier)
    #pragma unroll
    for (int r = 0; r < 4; ++r) {
      pw[(rb + r) * 32 + lrow]      = (bf16_t)s0[r];
      pw[(rb + r) * 32 + 16 + lrow] = (bf16_t)s1[r];
    }
    bf16x8 pf = *(const bf16x8*)&pw[lrow * 32 + lko];
    // PV: B = V[j][d] from Vt (contiguous in j)
    #pragma unroll
    for (int d = 0; d < 4; ++d) {
      bf16x8 vf = *(const bf16x8*)&Vbh[(size_t)(d * 16 + lrow) * NT + j0 + lko];
      acc[d] = __builtin_amdgcn_mfma_f32_16x16x32_bf16(pf, vf, acc[d], 0, 0, 0);
    }
  }

  // normalize + store ctx (B,T,D) bf16
  #pragma unroll
  for (int r = 0; r < 4; ++r) {
    float inv = 1.f / lsum[r];
    int gi = r0 + rb + r;
    size_t orow = ((size_t)b * NT + gi) * ND + h * NDH;
    #pragma unroll
    for (int d = 0; d < 4; ++d)
      ctx[orow + d * 16 + lrow] = (bf16_t)(acc[d][r] * inv);
  }
}

extern "C" void kernel_launch(void* const* d_in, const int* in_sizes, int n_in,
                              void* d_out, int out_size, void* d_ws, size_t ws_size,
                              hipStream_t stream) {
  const float* q  = (const float*)d_in[0];
  const float* k  = (const float*)d_in[1];
  const float* v  = (const float*)d_in[2];
  const float* Wq = (const float*)d_in[3];
  const float* bq = (const float*)d_in[4];
  const float* Wk = (const float*)d_in[5];
  const float* bk = (const float*)d_in[6];
  const float* Wv = (const float*)d_in[7];
  const float* bv = (const float*)d_in[8];
  const float* Wo = (const float*)d_in[9];
  const float* bo = (const float*)d_in[10];
  float* out = (float*)d_out;

  char* ws = (char*)d_ws;
  const size_t szMK = (size_t)NM * ND * sizeof(bf16_t);  // 16.78 MB
  const size_t szW  = (size_t)ND * ND * sizeof(bf16_t);  // 2 MB
  bf16_t* xb  = (bf16_t*)(ws);                 // activations scratch / ctx
  bf16_t* Qh  = (bf16_t*)(ws + szMK);
  bf16_t* Kh  = (bf16_t*)(ws + 2 * szMK);
  bf16_t* Vt  = (bf16_t*)(ws + 3 * szMK);
  bf16_t* Wqt = (bf16_t*)(ws + 4 * szMK);
  bf16_t* Wkt = (bf16_t*)(ws + 4 * szMK + szW);
  bf16_t* Wvt = (bf16_t*)(ws + 4 * szMK + 2 * szW);
  bf16_t* Wot = (bf16_t*)(ws + 4 * szMK + 3 * szW);

  dim3 tb(256);
  dim3 tg(ND / 32, ND / 32);
  transpose_cvt_kernel<<<tg, tb, 0, stream>>>(Wq, Wqt);
  transpose_cvt_kernel<<<tg, tb, 0, stream>>>(Wk, Wkt);
  transpose_cvt_kernel<<<tg, tb, 0, stream>>>(Wv, Wvt);
  transpose_cvt_kernel<<<tg, tb, 0, stream>>>(Wo, Wot);

  const int n4 = NM * ND / 4;
  dim3 cg((n4 + 255) / 256);
  dim3 gg(NM / 128, ND / 128);

  cvt_f32_to_bf16<<<cg, tb, 0, stream>>>(q, xb, n4);
  gemm_bt<0><<<gg, tb, 0, stream>>>(xb, Wqt, bq, Qh, NM, ND, ND);
  cvt_f32_to_bf16<<<cg, tb, 0, stream>>>(k, xb, n4);
  gemm_bt<0><<<gg, tb, 0, stream>>>(xb, Wkt, bk, Kh, NM, ND, ND);
  cvt_f32_to_bf16<<<cg, tb, 0, stream>>>(v, xb, n4);
  gemm_bt<1><<<gg, tb, 0, stream>>>(xb, Wvt, bv, Vt, NM, ND, ND);

  attn_kernel<<<dim3(NB * NH * (NT / 64)), tb, 0, stream>>>(Qh, Kh, Vt, xb);

  gemm_bt<2><<<gg, tb, 0, stream>>>(xb, Wot, bo, out, NM, ND, ND);
}

// Round 2
// 290.678 us; speedup vs baseline: 2.2487x; 2.2487x over previous
//
#include <hip/hip_runtime.h>
#include <hip/hip_bf16.h>

#define NB 4
#define NT 2048
#define ND 1024
#define NH 16
#define NDH 64
#define NM (NB*NT)   // 8192 rows

typedef __bf16 bf16_t;
typedef bf16_t bf16x4 __attribute__((ext_vector_type(4)));
typedef bf16_t bf16x8 __attribute__((ext_vector_type(8)));
typedef float f32x4 __attribute__((ext_vector_type(4)));

__device__ __forceinline__ void gload_lds16(const bf16_t* g, bf16_t* l) {
  __builtin_amdgcn_global_load_lds(
      (const __attribute__((address_space(1))) unsigned int*)g,
      (__attribute__((address_space(3))) unsigned int*)l, 16, 0, 0);
}

// ---------------- fp32 -> bf16 convert (vectorized) ----------------
__global__ void cvt_f32_to_bf16(const float* __restrict__ in, bf16_t* __restrict__ out, int n4) {
  int i = blockIdx.x * blockDim.x + threadIdx.x;
  if (i >= n4) return;
  float4 v = ((const float4*)in)[i];
  bf16x4 o;
  o[0] = (bf16_t)v.x; o[1] = (bf16_t)v.y; o[2] = (bf16_t)v.z; o[3] = (bf16_t)v.w;
  ((bf16x4*)out)[i] = o;
}

// ---------------- W (K x N fp32) -> W^T (N x K bf16) ----------------
__global__ void transpose_cvt_kernel(const float* __restrict__ in, bf16_t* __restrict__ out) {
  __shared__ float tile[32][33];
  int n0 = blockIdx.x * 32, k0 = blockIdx.y * 32;
  int tx = threadIdx.x & 31, ty = threadIdx.x >> 5;
  #pragma unroll
  for (int r = ty; r < 32; r += 8)
    tile[r][tx] = in[(size_t)(k0 + r) * ND + n0 + tx];
  __syncthreads();
  #pragma unroll
  for (int r = ty; r < 32; r += 8)
    out[(size_t)(n0 + r) * ND + k0 + tx] = (bf16_t)tile[tx][r];
}

// ---------------- GEMM: C = A(MxK bf16) * B^T(NxK bf16) + bias ----------------
// OUT_MODE 0: bf16 out, head layout (B,H,T,DH)   [Q,K projections]
// OUT_MODE 1: bf16 out, V^T layout (B,H,DH,T)    [V projection]
// OUT_MODE 2: fp32 out, row-major (M,N)          [output projection]
template<int OUT_MODE>
__global__ void gemm_bt(const bf16_t* __restrict__ A, const bf16_t* __restrict__ Bt,
                        const float* __restrict__ bias, void* __restrict__ outp,
                        int M, int N, int K) {
  __shared__ bf16_t As[128 * 32];
  __shared__ bf16_t Bs[128 * 32];
  const int tid  = threadIdx.x;
  const int lane = tid & 63;
  const int wid  = tid >> 6;
  const int tm = blockIdx.x * 128;
  const int tn = blockIdx.y * 128;
  const int wr = wid >> 1, wc = wid & 1;
  const int lrow = lane & 15;
  const int lko  = (lane >> 4) << 3;

  const int cA  = wid * 64 + lane;
  const int rA0 = cA >> 2;
  const int kA0 = (cA & 3) << 3;

  f32x4 acc[4][4];
  #pragma unroll
  for (int i = 0; i < 4; ++i)
    #pragma unroll
    for (int j = 0; j < 4; ++j) {
      f32x4 z = {0.f, 0.f, 0.f, 0.f};
      acc[i][j] = z;
    }

  for (int k0 = 0; k0 < K; k0 += 32) {
    gload_lds16(A  + (size_t)(tm + rA0)      * K + k0 + kA0, As + wid * 512);
    gload_lds16(A  + (size_t)(tm + rA0 + 64) * K + k0 + kA0, As + 2048 + wid * 512);
    gload_lds16(Bt + (size_t)(tn + rA0)      * K + k0 + kA0, Bs + wid * 512);
    gload_lds16(Bt + (size_t)(tn + rA0 + 64) * K + k0 + kA0, Bs + 2048 + wid * 512);
    __syncthreads();
    bf16x8 af[4], bfr[4];
    #pragma unroll
    for (int i = 0; i < 4; ++i)
      af[i] = *(const bf16x8*)&As[(wr * 64 + i * 16 + lrow) * 32 + lko];
    #pragma unroll
    for (int j = 0; j < 4; ++j)
      bfr[j] = *(const bf16x8*)&Bs[(wc * 64 + j * 16 + lrow) * 32 + lko];
    #pragma unroll
    for (int i = 0; i < 4; ++i)
      #pragma unroll
      for (int j = 0; j < 4; ++j)
        acc[i][j] = __builtin_amdgcn_mfma_f32_16x16x32_bf16(af[i], bfr[j], acc[i][j], 0, 0, 0);
    __syncthreads();
  }

  const int rb = (lane >> 4) << 2;
  #pragma unroll
  for (int j = 0; j < 4; ++j) {
    int n = tn + wc * 64 + j * 16 + lrow;
    float bv = bias[n];
    #pragma unroll
    for (int i = 0; i < 4; ++i) {
      #pragma unroll
      for (int r = 0; r < 4; ++r) {
        int m = tm + wr * 64 + i * 16 + rb + r;
        float val = acc[i][j][r] + bv;
        if constexpr (OUT_MODE == 2) {
          ((float*)outp)[(size_t)m * ND + n] = val;
        } else {
          int b = m >> 11, t = m & (NT - 1);
          int h = n >> 6, dh = n & (NDH - 1);
          size_t idx;
          if constexpr (OUT_MODE == 0)
            idx = ((size_t)(b * NH + h) * NT + t) * NDH + dh;
          else
            idx = ((size_t)(b * NH + h) * NDH + dh) * NT + t;
          ((bf16_t*)outp)[idx] = (bf16_t)val;
        }
      }
    }
  }
}

// ---------------- causal flash attention (LDS-staged, double-buffered) ----------------
// Qh,Kh: (B,H,T,DH) bf16; Vt: (B,H,DH,T) bf16; ctx out: (B,T,D) bf16 row-major
// Block: 256 thr = 4 waves, each wave 16 q-rows -> QBLK=64. KV tile = 64.
// Each block processes q-tile pair (p, 31-p): uniform 33 KV tiles of work.

__device__ __forceinline__ bf16x8 lds_swz_read(const bf16_t* base, int row, int colb) {
  return *(const bf16x8*)((const char*)base + row * 128 + (colb ^ ((row & 7) << 4)));
}

// stage one 64x64 K tile (contiguous) + one 64x64 V tile (rows strided NT)
__device__ __forceinline__ void stage_tile(const bf16_t* Kbh, const bf16_t* Vbh, int j0,
                                           bf16_t* ksBuf, bf16_t* vsBuf, int wid, int lane) {
  const char* gK = (const char*)(Kbh + (size_t)j0 * NDH);
  #pragma unroll
  for (int c = 0; c < 2; ++c) {
    int o = c * 4096 + wid * 1024 + lane * 16;   // dest byte offset in tile
    int row = o >> 7;                             // 128B per row
    int srcb = o ^ ((row & 7) << 4);              // inverse swizzle on source
    gload_lds16((const bf16_t*)(gK + srcb),
                (bf16_t*)((char*)ksBuf + c * 4096 + wid * 1024));
  }
  #pragma unroll
  for (int c = 0; c < 2; ++c) {
    int o = c * 4096 + wid * 1024 + lane * 16;
    int row = o >> 7;                             // dh row
    int colb = (o & 127) ^ ((row & 7) << 4);
    const bf16_t* src = Vbh + (size_t)row * NT + j0 + (colb >> 1);
    gload_lds16(src, (bf16_t*)((char*)vsBuf + c * 4096 + wid * 1024));
  }
}

__global__ __launch_bounds__(256) void attn_kernel(
    const bf16_t* __restrict__ Qh, const bf16_t* __restrict__ Kh,
    const bf16_t* __restrict__ Vt, bf16_t* __restrict__ ctx) {
  __shared__ bf16_t Ks[2][64 * 64];
  __shared__ bf16_t Vs[2][64 * 64];
  __shared__ bf16_t Pl[4][16 * 64];
  const int tid  = threadIdx.x;
  const int lane = tid & 63;
  const int wid  = tid >> 6;
  const int bh      = blockIdx.x >> 4;   // (b*H + h)
  const int pairIdx = blockIdx.x & 15;
  const int b = bh >> 4, h = bh & 15;

  const bf16_t* Qbh = Qh + (size_t)bh * NT * NDH;
  const bf16_t* Kbh = Kh + (size_t)bh * NT * NDH;
  const bf16_t* Vbh = Vt + (size_t)bh * NDH * NT;

  const int lrow = lane & 15;
  const int lg   = lane >> 4;
  const int rb   = lg << 2;
  bf16_t* pw = &Pl[wid][0];

  #pragma unroll 1
  for (int half = 0; half < 2; ++half) {
    const int qidx = half ? (31 - pairIdx) : pairIdx;
    const int r0   = qidx * 64 + wid * 16;

    bf16x8 qf0 = *(const bf16x8*)&Qbh[(size_t)(r0 + lrow) * NDH + lg * 8];
    bf16x8 qf1 = *(const bf16x8*)&Qbh[(size_t)(r0 + lrow) * NDH + 32 + lg * 8];

    float mrow[4], lsum[4];
    f32x4 acc[4];
    #pragma unroll
    for (int r = 0; r < 4; ++r) { mrow[r] = -1e30f; lsum[r] = 0.f; }
    #pragma unroll
    for (int d = 0; d < 4; ++d) { f32x4 z = {0.f, 0.f, 0.f, 0.f}; acc[d] = z; }

    __syncthreads();                       // protect LDS bufs from previous half
    stage_tile(Kbh, Vbh, 0, Ks[0], Vs[0], wid, lane);
    int cur = 0;

    #pragma unroll 1
    for (int t = 0; t <= qidx; ++t) {
      // stage(t) landed for all waves; all waves done reading buf cur^1
      asm volatile("s_waitcnt vmcnt(0)\n\ts_barrier" ::: "memory");
      if (t < qidx)
        stage_tile(Kbh, Vbh, (t + 1) * 64, Ks[cur ^ 1], Vs[cur ^ 1], wid, lane);

      const bf16_t* ksCur = Ks[cur];
      const bf16_t* vsCur = Vs[cur];

      // ---- QK^T: 16 q-rows x 64 kv ----
      f32x4 sg[4];
      #pragma unroll
      for (int g = 0; g < 4; ++g) { f32x4 z = {0.f, 0.f, 0.f, 0.f}; sg[g] = z; }
      #pragma unroll
      for (int g = 0; g < 4; ++g) {
        bf16x8 kfa = lds_swz_read(ksCur, g * 16 + lrow, lg * 16);
        sg[g] = __builtin_amdgcn_mfma_f32_16x16x32_bf16(qf0, kfa, sg[g], 0, 0, 0);
        bf16x8 kfb = lds_swz_read(ksCur, g * 16 + lrow, 64 + lg * 16);
        sg[g] = __builtin_amdgcn_mfma_f32_16x16x32_bf16(qf1, kfb, sg[g], 0, 0, 0);
      }

      // ---- scale + causal mask + online softmax ----
      const int jb = t * 64;
      const bool lastT = (t == qidx);
      float pm[4];
      #pragma unroll
      for (int r = 0; r < 4; ++r) pm[r] = -1e30f;
      #pragma unroll
      for (int g = 0; g < 4; ++g)
        #pragma unroll
        for (int r = 0; r < 4; ++r) {
          float x = sg[g][r] * 0.125f;
          if (lastT && (jb + g * 16 + lrow > r0 + rb + r)) x = -1e30f;
          sg[g][r] = x;
          pm[r] = fmaxf(pm[r], x);
        }
      #pragma unroll
      for (int off = 1; off < 16; off <<= 1)
        #pragma unroll
        for (int r = 0; r < 4; ++r) pm[r] = fmaxf(pm[r], __shfl_xor(pm[r], off));

      float psum[4];
      #pragma unroll
      for (int r = 0; r < 4; ++r) {
        float mn = fmaxf(mrow[r], pm[r]);
        float alpha = __expf(mrow[r] - mn);
        mrow[r] = mn;
        lsum[r] *= alpha;
        acc[0][r] *= alpha; acc[1][r] *= alpha; acc[2][r] *= alpha; acc[3][r] *= alpha;
        psum[r] = 0.f;
      }
      #pragma unroll
      for (int g = 0; g < 4; ++g)
        #pragma unroll
        for (int r = 0; r < 4; ++r) {
          float p = __expf(sg[g][r] - mrow[r]);
          sg[g][r] = p;
          psum[r] += p;
        }
      #pragma unroll
      for (int off = 1; off < 16; off <<= 1)
        #pragma unroll
        for (int r = 0; r < 4; ++r) psum[r] += __shfl_xor(psum[r], off);
      #pragma unroll
      for (int r = 0; r < 4; ++r) lsum[r] += psum[r];

      // ---- P (D-layout) -> LDS (swizzled) -> A-layout frags (wave-private) ----
      #pragma unroll
      for (int g = 0; g < 4; ++g)
        #pragma unroll
        for (int r = 0; r < 4; ++r) {
          int prow = rb + r;
          *(bf16_t*)((char*)pw + prow * 128 +
                     ((((g * 16 + lrow) * 2)) ^ ((prow & 7) << 4))) = (bf16_t)sg[g][r];
        }
      bf16x8 pf0 = lds_swz_read(pw, lrow, lg * 16);
      bf16x8 pf1 = lds_swz_read(pw, lrow, 64 + lg * 16);

      // ---- PV ----
      #pragma unroll
      for (int d = 0; d < 4; ++d) {
        bf16x8 vf0 = lds_swz_read(vsCur, d * 16 + lrow, lg * 16);
        acc[d] = __builtin_amdgcn_mfma_f32_16x16x32_bf16(pf0, vf0, acc[d], 0, 0, 0);
        bf16x8 vf1 = lds_swz_read(vsCur, d * 16 + lrow, 64 + lg * 16);
        acc[d] = __builtin_amdgcn_mfma_f32_16x16x32_bf16(pf1, vf1, acc[d], 0, 0, 0);
      }

      cur ^= 1;
    }

    // ---- normalize + store ctx (B,T,D) bf16 ----
    #pragma unroll
    for (int r = 0; r < 4; ++r) {
      float inv = 1.f / lsum[r];
      int gi = r0 + rb + r;
      size_t orow = ((size_t)b * NT + gi) * ND + h * NDH;
      #pragma unroll
      for (int d = 0; d < 4; ++d)
        ctx[orow + d * 16 + lrow] = (bf16_t)(acc[d][r] * inv);
    }
  }
}

extern "C" void kernel_launch(void* const* d_in, const int* in_sizes, int n_in,
                              void* d_out, int out_size, void* d_ws, size_t ws_size,
                              hipStream_t stream) {
  const float* q  = (const float*)d_in[0];
  const float* k  = (const float*)d_in[1];
  const float* v  = (const float*)d_in[2];
  const float* Wq = (const float*)d_in[3];
  const float* bq = (const float*)d_in[4];
  const float* Wk = (const float*)d_in[5];
  const float* bk = (const float*)d_in[6];
  const float* Wv = (const float*)d_in[7];
  const float* bv = (const float*)d_in[8];
  const float* Wo = (const float*)d_in[9];
  const float* bo = (const float*)d_in[10];
  float* out = (float*)d_out;

  char* ws = (char*)d_ws;
  const size_t szMK = (size_t)NM * ND * sizeof(bf16_t);  // 16.78 MB
  const size_t szW  = (size_t)ND * ND * sizeof(bf16_t);  // 2 MB
  bf16_t* xb  = (bf16_t*)(ws);                 // activations scratch / ctx
  bf16_t* Qh  = (bf16_t*)(ws + szMK);
  bf16_t* Kh  = (bf16_t*)(ws + 2 * szMK);
  bf16_t* Vt  = (bf16_t*)(ws + 3 * szMK);
  bf16_t* Wqt = (bf16_t*)(ws + 4 * szMK);
  bf16_t* Wkt = (bf16_t*)(ws + 4 * szMK + szW);
  bf16_t* Wvt = (bf16_t*)(ws + 4 * szMK + 2 * szW);
  bf16_t* Wot = (bf16_t*)(ws + 4 * szMK + 3 * szW);

  dim3 tb(256);
  dim3 tg(ND / 32, ND / 32);
  transpose_cvt_kernel<<<tg, tb, 0, stream>>>(Wq, Wqt);
  transpose_cvt_kernel<<<tg, tb, 0, stream>>>(Wk, Wkt);
  transpose_cvt_kernel<<<tg, tb, 0, stream>>>(Wv, Wvt);
  transpose_cvt_kernel<<<tg, tb, 0, stream>>>(Wo, Wot);

  const int n4 = NM * ND / 4;
  dim3 cg((n4 + 255) / 256);
  dim3 gg(NM / 128, ND / 128);

  cvt_f32_to_bf16<<<cg, tb, 0, stream>>>(q, xb, n4);
  gemm_bt<0><<<gg, tb, 0, stream>>>(xb, Wqt, bq, Qh, NM, ND, ND);
  cvt_f32_to_bf16<<<cg, tb, 0, stream>>>(k, xb, n4);
  gemm_bt<0><<<gg, tb, 0, stream>>>(xb, Wkt, bk, Kh, NM, ND, ND);
  cvt_f32_to_bf16<<<cg, tb, 0, stream>>>(v, xb, n4);
  gemm_bt<1><<<gg, tb, 0, stream>>>(xb, Wvt, bv, Vt, NM, ND, ND);

  attn_kernel<<<dim3(NB * NH * 16), tb, 0, stream>>>(Qh, Kh, Vt, xb);

  gemm_bt<2><<<gg, tb, 0, stream>>>(xb, Wot, bo, out, NM, ND, ND);
}

// Round 3
// 229.994 us; speedup vs baseline: 2.8420x; 1.2638x over previous
//
#include <hip/hip_runtime.h>
#include <hip/hip_bf16.h>

#define NB 4
#define NT 2048
#define ND 1024
#define NH 16
#define NDH 64
#define NM (NB*NT)   // 8192 rows

typedef __bf16 bf16_t;
typedef bf16_t bf16x4 __attribute__((ext_vector_type(4)));
typedef bf16_t bf16x8 __attribute__((ext_vector_type(8)));
typedef float f32x4 __attribute__((ext_vector_type(4)));
typedef unsigned int u32x4 __attribute__((ext_vector_type(4)));

__device__ __forceinline__ void gload_lds16(const bf16_t* g, bf16_t* l) {
  __builtin_amdgcn_global_load_lds(
      (const __attribute__((address_space(1))) unsigned int*)g,
      (__attribute__((address_space(3))) unsigned int*)l, 16, 0, 0);
}

// ---------------- fp32 -> bf16 convert (vectorized) ----------------
__global__ void cvt_f32_to_bf16(const float* __restrict__ in, bf16_t* __restrict__ out, int n4) {
  int i = blockIdx.x * blockDim.x + threadIdx.x;
  if (i >= n4) return;
  float4 v = ((const float4*)in)[i];
  bf16x4 o;
  o[0] = (bf16_t)v.x; o[1] = (bf16_t)v.y; o[2] = (bf16_t)v.z; o[3] = (bf16_t)v.w;
  ((bf16x4*)out)[i] = o;
}

// ---------------- W (K x N fp32) -> W^T (N x K bf16), 4 fused ----------------
__global__ void transpose_cvt4(const float* __restrict__ w0, const float* __restrict__ w1,
                               const float* __restrict__ w2, const float* __restrict__ w3,
                               bf16_t* __restrict__ o0, bf16_t* __restrict__ o1,
                               bf16_t* __restrict__ o2, bf16_t* __restrict__ o3) {
  __shared__ float tile[32][33];
  const float* in = blockIdx.z == 0 ? w0 : blockIdx.z == 1 ? w1 : blockIdx.z == 2 ? w2 : w3;
  bf16_t* out     = blockIdx.z == 0 ? o0 : blockIdx.z == 1 ? o1 : blockIdx.z == 2 ? o2 : o3;
  int n0 = blockIdx.x * 32, k0 = blockIdx.y * 32;
  int tx = threadIdx.x & 31, ty = threadIdx.x >> 5;
  #pragma unroll
  for (int r = ty; r < 32; r += 8)
    tile[r][tx] = in[(size_t)(k0 + r) * ND + n0 + tx];
  __syncthreads();
  #pragma unroll
  for (int r = ty; r < 32; r += 8)
    out[(size_t)(n0 + r) * ND + k0 + tx] = (bf16_t)tile[tx][r];
}

// ---------------- GEMM: C = (A(MxK bf16) * B^T(NxK bf16) + bias) * scale ----------------
// OUT_MODE 0: bf16 out, head layout (B,H,T,DH)   [Q,K projections]
// OUT_MODE 1: bf16 out, V^T layout (B,H,DH,T)    [V projection]
// OUT_MODE 2: fp32 out, row-major (M,N)          [output projection]
template<int OUT_MODE>
__global__ void gemm_bt(const bf16_t* __restrict__ A, const bf16_t* __restrict__ Bt,
                        const float* __restrict__ bias, void* __restrict__ outp,
                        int M, int N, int K, float scale) {
  __shared__ bf16_t As[128 * 32];
  __shared__ bf16_t Bs[128 * 32];
  const int tid  = threadIdx.x;
  const int lane = tid & 63;
  const int wid  = tid >> 6;
  const int tm = blockIdx.x * 128;
  const int tn = blockIdx.y * 128;
  const int wr = wid >> 1, wc = wid & 1;
  const int lrow = lane & 15;
  const int lko  = (lane >> 4) << 3;

  const int cA  = wid * 64 + lane;
  const int rA0 = cA >> 2;
  const int kA0 = (cA & 3) << 3;

  f32x4 acc[4][4];
  #pragma unroll
  for (int i = 0; i < 4; ++i)
    #pragma unroll
    for (int j = 0; j < 4; ++j) {
      f32x4 z = {0.f, 0.f, 0.f, 0.f};
      acc[i][j] = z;
    }

  for (int k0 = 0; k0 < K; k0 += 32) {
    gload_lds16(A  + (size_t)(tm + rA0)      * K + k0 + kA0, As + wid * 512);
    gload_lds16(A  + (size_t)(tm + rA0 + 64) * K + k0 + kA0, As + 2048 + wid * 512);
    gload_lds16(Bt + (size_t)(tn + rA0)      * K + k0 + kA0, Bs + wid * 512);
    gload_lds16(Bt + (size_t)(tn + rA0 + 64) * K + k0 + kA0, Bs + 2048 + wid * 512);
    __syncthreads();
    bf16x8 af[4], bfr[4];
    #pragma unroll
    for (int i = 0; i < 4; ++i)
      af[i] = *(const bf16x8*)&As[(wr * 64 + i * 16 + lrow) * 32 + lko];
    #pragma unroll
    for (int j = 0; j < 4; ++j)
      bfr[j] = *(const bf16x8*)&Bs[(wc * 64 + j * 16 + lrow) * 32 + lko];
    #pragma unroll
    for (int i = 0; i < 4; ++i)
      #pragma unroll
      for (int j = 0; j < 4; ++j)
        acc[i][j] = __builtin_amdgcn_mfma_f32_16x16x32_bf16(af[i], bfr[j], acc[i][j], 0, 0, 0);
    __syncthreads();
  }

  const int rb = (lane >> 4) << 2;
  #pragma unroll
  for (int j = 0; j < 4; ++j) {
    int n = tn + wc * 64 + j * 16 + lrow;
    float bv = bias[n];
    #pragma unroll
    for (int i = 0; i < 4; ++i) {
      #pragma unroll
      for (int r = 0; r < 4; ++r) {
        int m = tm + wr * 64 + i * 16 + rb + r;
        float val = (acc[i][j][r] + bv) * scale;
        if constexpr (OUT_MODE == 2) {
          ((float*)outp)[(size_t)m * ND + n] = val;
        } else {
          int b = m >> 11, t = m & (NT - 1);
          int h = n >> 6, dh = n & (NDH - 1);
          size_t idx;
          if constexpr (OUT_MODE == 0)
            idx = ((size_t)(b * NH + h) * NT + t) * NDH + dh;
          else
            idx = ((size_t)(b * NH + h) * NDH + dh) * NT + t;
          ((bf16_t*)outp)[idx] = (bf16_t)val;
        }
      }
    }
  }
}

// ---------------- causal flash attention (LDS-staged, swapped-QK, in-reg softmax) ----------------
// Qh,Kh: (B,H,T,DH) bf16 (Q pre-scaled by 1/8); Vt: (B,H,DH,T) bf16; ctx out: (B,T,D) bf16
// Block: 256 thr = 4 waves, each wave 16 q-rows -> QBLK=64. KV tile = 64.
// Block processes q-tile pair (p, 31-p): uniform 33 KV tiles.

__device__ __forceinline__ bf16x8 lds_swz_read(const bf16_t* base, int row, int colb) {
  return *(const bf16x8*)((const char*)base + row * 128 + (colb ^ ((row & 7) << 4)));
}

__device__ __forceinline__ void stage_tile(const bf16_t* Kbh, const bf16_t* Vbh, int j0,
                                           bf16_t* ksBuf, bf16_t* vsBuf, int wid, int lane) {
  const char* gK = (const char*)(Kbh + (size_t)j0 * NDH);
  #pragma unroll
  for (int c = 0; c < 2; ++c) {
    int o = c * 4096 + wid * 1024 + lane * 16;   // dest byte offset in tile
    int row = o >> 7;                             // 128B per row
    int srcb = o ^ ((row & 7) << 4);              // inverse swizzle on source
    gload_lds16((const bf16_t*)(gK + srcb),
                (bf16_t*)((char*)ksBuf + c * 4096 + wid * 1024));
  }
  #pragma unroll
  for (int c = 0; c < 2; ++c) {
    int o = c * 4096 + wid * 1024 + lane * 16;
    int row = o >> 7;                             // dh row
    int colb = (o & 127) ^ ((row & 7) << 4);
    const bf16_t* src = Vbh + (size_t)row * NT + j0 + (colb >> 1);
    gload_lds16(src, (bf16_t*)((char*)vsBuf + c * 4096 + wid * 1024));
  }
}

#define CVTPK(lo, hi) ({ unsigned r_; \
  asm("v_cvt_pk_bf16_f32 %0, %1, %2" : "=v"(r_) : "v"(lo), "v"(hi)); r_; })

__global__ __launch_bounds__(256) void attn_kernel(
    const bf16_t* __restrict__ Qh, const bf16_t* __restrict__ Kh,
    const bf16_t* __restrict__ Vt, bf16_t* __restrict__ ctx) {
  __shared__ bf16_t Ks[2][64 * 64];
  __shared__ bf16_t Vs[2][64 * 64];
  const int tid  = threadIdx.x;
  const int lane = tid & 63;
  const int wid  = tid >> 6;
  const int bh      = blockIdx.x >> 4;   // (b*H + h)
  const int pairIdx = blockIdx.x & 15;
  const int b = bh >> 4, h = bh & 15;

  const bf16_t* Qbh = Qh + (size_t)bh * NT * NDH;
  const bf16_t* Kbh = Kh + (size_t)bh * NT * NDH;
  const bf16_t* Vbh = Vt + (size_t)bh * NDH * NT;

  const int lrow = lane & 15;   // q column in S^T / ctx^T
  const int lg   = lane >> 4;

  #pragma unroll 1
  for (int half = 0; half < 2; ++half) {
    const int qidx = half ? (31 - pairIdx) : pairIdx;
    const int r0   = qidx * 64 + wid * 16;
    const int qg   = r0 + lrow;           // this lane's global q row

    bf16x8 qf0 = *(const bf16x8*)&Qbh[(size_t)(r0 + lrow) * NDH + lg * 8];
    bf16x8 qf1 = *(const bf16x8*)&Qbh[(size_t)(r0 + lrow) * NDH + 32 + lg * 8];

    float mrow = -1e30f, lsum = 0.f;
    f32x4 acc[4];
    #pragma unroll
    for (int d = 0; d < 4; ++d) { f32x4 z = {0.f, 0.f, 0.f, 0.f}; acc[d] = z; }

    __syncthreads();                       // protect LDS bufs from previous half
    stage_tile(Kbh, Vbh, 0, Ks[0], Vs[0], wid, lane);
    int cur = 0;

    #pragma unroll 1
    for (int t = 0; t <= qidx; ++t) {
      asm volatile("s_waitcnt vmcnt(0)\n\ts_barrier" ::: "memory");
      if (t < qidx)
        stage_tile(Kbh, Vbh, (t + 1) * 64, Ks[cur ^ 1], Vs[cur ^ 1], wid, lane);

      const bf16_t* ksCur = Ks[cur];
      const bf16_t* vsCur = Vs[cur];

      // ---- QK^T swapped: S^T[kv][q]; lane owns q=lrow, kv = g*16 + lg*4 + r ----
      f32x4 sg[4];
      #pragma unroll
      for (int g = 0; g < 4; ++g) { f32x4 z = {0.f, 0.f, 0.f, 0.f}; sg[g] = z; }
      __builtin_amdgcn_s_setprio(1);
      #pragma unroll
      for (int g = 0; g < 4; ++g) {
        bf16x8 kfa = lds_swz_read(ksCur, g * 16 + lrow, lg * 16);
        sg[g] = __builtin_amdgcn_mfma_f32_16x16x32_bf16(kfa, qf0, sg[g], 0, 0, 0);
        bf16x8 kfb = lds_swz_read(ksCur, g * 16 + lrow, 64 + lg * 16);
        sg[g] = __builtin_amdgcn_mfma_f32_16x16x32_bf16(kfb, qf1, sg[g], 0, 0, 0);
      }
      __builtin_amdgcn_s_setprio(0);

      // ---- causal mask (diag tile only) ----
      const int jb = t * 64;
      if (t == qidx) {
        #pragma unroll
        for (int g = 0; g < 4; ++g)
          #pragma unroll
          for (int r = 0; r < 4; ++r)
            if (jb + g * 16 + lg * 4 + r > qg) sg[g][r] = -1e30f;
      }

      // ---- row max: in-lane tree + 2 shuffles ----
      float gm[4];
      #pragma unroll
      for (int g = 0; g < 4; ++g)
        gm[g] = fmaxf(fmaxf(sg[g][0], sg[g][1]), fmaxf(sg[g][2], sg[g][3]));
      float pm = fmaxf(fmaxf(gm[0], gm[1]), fmaxf(gm[2], gm[3]));
      pm = fmaxf(pm, __shfl_xor(pm, 16));
      pm = fmaxf(pm, __shfl_xor(pm, 32));

      // ---- defer-max rescale (THR=8) ----
      if (!__all(pm <= mrow + 8.0f)) {
        float mn = fmaxf(mrow, pm);
        float alpha = __expf(mrow - mn);
        mrow = mn;
        lsum *= alpha;
        #pragma unroll
        for (int d = 0; d < 4; ++d)
          #pragma unroll
          for (int r = 0; r < 4; ++r) acc[d][r] *= alpha;
      }

      // ---- exp + row sum ----
      float ps = 0.f;
      #pragma unroll
      for (int g = 0; g < 4; ++g) {
        #pragma unroll
        for (int r = 0; r < 4; ++r) {
          float p = __expf(sg[g][r] - mrow);
          sg[g][r] = p;
          ps += p;
        }
      }
      ps += __shfl_xor(ps, 16);
      ps += __shfl_xor(ps, 32);
      lsum += ps;

      // ---- P^T -> bf16 B-fragments fully in-register ----
      // W[g][t] = packed bf16 pair (kv = g*16+lg*4+2t, +1) for q=lrow
      unsigned W00 = CVTPK(sg[0][0], sg[0][1]), W01 = CVTPK(sg[0][2], sg[0][3]);
      unsigned W10 = CVTPK(sg[1][0], sg[1][1]), W11 = CVTPK(sg[1][2], sg[1][3]);
      unsigned W20 = CVTPK(sg[2][0], sg[2][1]), W21 = CVTPK(sg[2][2], sg[2][3]);
      unsigned W30 = CVTPK(sg[3][0], sg[3][1]), W31 = CVTPK(sg[3][2], sg[3][3]);
      // chunk 0 (kv 0..31): a=W[0][t], b=W[1][t]; chunk 1: a=W[2][t], b=W[3][t]
      // permlane32_swap: a'={a_lo,b_lo}, b'={a_hi,b_hi}; permlane16_swap: mixes 16-groups
      unsigned w00, w01, w02, w03, w10, w11, w12, w13;
      { unsigned a = W00, bb = W10;
        asm("v_permlane32_swap_b32 %0, %1" : "+v"(a), "+v"(bb));
        asm("v_permlane16_swap_b32 %0, %1" : "+v"(a), "+v"(bb));
        w00 = a; w02 = bb; }
      { unsigned a = W01, bb = W11;
        asm("v_permlane32_swap_b32 %0, %1" : "+v"(a), "+v"(bb));
        asm("v_permlane16_swap_b32 %0, %1" : "+v"(a), "+v"(bb));
        w01 = a; w03 = bb; }
      { unsigned a = W20, bb = W30;
        asm("v_permlane32_swap_b32 %0, %1" : "+v"(a), "+v"(bb));
        asm("v_permlane16_swap_b32 %0, %1" : "+v"(a), "+v"(bb));
        w10 = a; w12 = bb; }
      { unsigned a = W21, bb = W31;
        asm("v_permlane32_swap_b32 %0, %1" : "+v"(a), "+v"(bb));
        asm("v_permlane16_swap_b32 %0, %1" : "+v"(a), "+v"(bb));
        w11 = a; w13 = bb; }
      u32x4 c0 = {w00, w01, w02, w03};
      u32x4 c1 = {w10, w11, w12, w13};
      bf16x8 pf0 = __builtin_bit_cast(bf16x8, c0);
      bf16x8 pf1 = __builtin_bit_cast(bf16x8, c1);

      // ---- PV: ctx^T[d][q] = V^T(A) x P^T(B) ----
      __builtin_amdgcn_s_setprio(1);
      #pragma unroll
      for (int d = 0; d < 4; ++d) {
        bf16x8 vf0 = lds_swz_read(vsCur, d * 16 + lrow, lg * 16);
        acc[d] = __builtin_amdgcn_mfma_f32_16x16x32_bf16(vf0, pf0, acc[d], 0, 0, 0);
        bf16x8 vf1 = lds_swz_read(vsCur, d * 16 + lrow, 64 + lg * 16);
        acc[d] = __builtin_amdgcn_mfma_f32_16x16x32_bf16(vf1, pf1, acc[d], 0, 0, 0);
      }
      __builtin_amdgcn_s_setprio(0);

      cur ^= 1;
    }

    // ---- normalize + store ctx (B,T,D) bf16; lane holds d = d2*16 + lg*4 + r at q = qg ----
    float inv = 1.f / lsum;
    size_t orow = ((size_t)b * NT + qg) * ND + h * NDH;
    #pragma unroll
    for (int d2 = 0; d2 < 4; ++d2) {
      bf16x4 o;
      #pragma unroll
      for (int r = 0; r < 4; ++r) o[r] = (bf16_t)(acc[d2][r] * inv);
      *(bf16x4*)&ctx[orow + d2 * 16 + lg * 4] = o;
    }
  }
}

extern "C" void kernel_launch(void* const* d_in, const int* in_sizes, int n_in,
                              void* d_out, int out_size, void* d_ws, size_t ws_size,
                              hipStream_t stream) {
  const float* q  = (const float*)d_in[0];
  const float* k  = (const float*)d_in[1];
  const float* v  = (const float*)d_in[2];
  const float* Wq = (const float*)d_in[3];
  const float* bq = (const float*)d_in[4];
  const float* Wk = (const float*)d_in[5];
  const float* bk = (const float*)d_in[6];
  const float* Wv = (const float*)d_in[7];
  const float* bv = (const float*)d_in[8];
  const float* Wo = (const float*)d_in[9];
  const float* bo = (const float*)d_in[10];
  float* out = (float*)d_out;

  char* ws = (char*)d_ws;
  const size_t szMK = (size_t)NM * ND * sizeof(bf16_t);  // 16.78 MB
  const size_t szW  = (size_t)ND * ND * sizeof(bf16_t);  // 2 MB
  bf16_t* xb  = (bf16_t*)(ws);                 // activations scratch / ctx
  bf16_t* Qh  = (bf16_t*)(ws + szMK);
  bf16_t* Kh  = (bf16_t*)(ws + 2 * szMK);
  bf16_t* Vt  = (bf16_t*)(ws + 3 * szMK);
  bf16_t* Wqt = (bf16_t*)(ws + 4 * szMK);
  bf16_t* Wkt = (bf16_t*)(ws + 4 * szMK + szW);
  bf16_t* Wvt = (bf16_t*)(ws + 4 * szMK + 2 * szW);
  bf16_t* Wot = (bf16_t*)(ws + 4 * szMK + 3 * szW);

  dim3 tb(256);
  transpose_cvt4<<<dim3(ND / 32, ND / 32, 4), tb, 0, stream>>>(Wq, Wk, Wv, Wo,
                                                               Wqt, Wkt, Wvt, Wot);

  const int n4 = NM * ND / 4;
  dim3 cg((n4 + 255) / 256);
  dim3 gg(NM / 128, ND / 128);

  cvt_f32_to_bf16<<<cg, tb, 0, stream>>>(q, xb, n4);
  gemm_bt<0><<<gg, tb, 0, stream>>>(xb, Wqt, bq, Qh, NM, ND, ND, 0.125f);
  cvt_f32_to_bf16<<<cg, tb, 0, stream>>>(k, xb, n4);
  gemm_bt<0><<<gg, tb, 0, stream>>>(xb, Wkt, bk, Kh, NM, ND, ND, 1.0f);
  cvt_f32_to_bf16<<<cg, tb, 0, stream>>>(v, xb, n4);
  gemm_bt<1><<<gg, tb, 0, stream>>>(xb, Wvt, bv, Vt, NM, ND, ND, 1.0f);

  attn_kernel<<<dim3(NB * NH * 16), tb, 0, stream>>>(Qh, Kh, Vt, xb);

  gemm_bt<2><<<gg, tb, 0, stream>>>(xb, Wot, bo, out, NM, ND, ND, 1.0f);
}